// Round 11
// baseline (148.163 us; speedup 1.0000x reference)
//
#include <hip/hip_runtime.h>
#include <math.h>

#define NB 32
#define NT 4096
#define ND 512
#define NA 64
#define ND4 (ND / 4)            // 128 float4 units per x-row
#define TR 16                   // rows per tile (one MFMA M-tile)
#define TPW 8                   // tiles per wave
#define NWAVE (NB * NT / (TR * TPW))   // 1024 waves
#define NPW (NWAVE / NB)        // 32 wave-partials per batch row

typedef __attribute__((ext_vector_type(8))) short short8;   // 8 bf16
typedef __attribute__((ext_vector_type(4))) float f32x4;    // MFMA acc

// ---- split-bf16 helpers: f = hi(trunc bf16) + lo(RNE bf16 of residual) ----
__device__ __forceinline__ uint rne16(float r) {
    uint v = __float_as_uint(r);
    v += 0x7fffu + ((v >> 16) & 1u);
    return v;
}
__device__ __forceinline__ void split2(float f0, float f1, uint& hw, uint& lw) {
    uint u0 = __float_as_uint(f0), u1 = __float_as_uint(f1);
    hw = (u0 >> 16) | (u1 & 0xffff0000u);
    float r0 = f0 - __uint_as_float(u0 & 0xffff0000u);
    float r1 = f1 - __uint_as_float(u1 & 0xffff0000u);
    lw = (rne16(r0) >> 16) | (rne16(r1) & 0xffff0000u);
}
__device__ __forceinline__ void split8(float4 a, float4 b, short8& hi, short8& lo) {
    union U { short8 s; uint u[4]; } H, L;
    split2(a.x, a.y, H.u[0], L.u[0]);
    split2(a.z, a.w, H.u[1], L.u[1]);
    split2(b.x, b.y, H.u[2], L.u[2]);
    split2(b.z, b.w, H.u[3], L.u[3]);
    hi = H.s; lo = L.s;
}

// ------------------------------------------------------------------ prep ----
// Pack W1 into MFMA B-fragments (hi/lo bf16), fidx == global thread id.
__global__ __launch_bounds__(256) void k_prep(
    const float* __restrict__ W1, short8* __restrict__ whi, short8* __restrict__ wlo)
{
    int t = blockIdx.x * 256 + threadIdx.x;       // 0..4095
    int l  = t & 63;
    int nt = (t >> 6) & 3;
    int ks = t >> 8;
    int a  = nt * 16 + (l & 15);
    int kb = ks * 32 + (l >> 4) * 8;
    const float* p = W1 + a * ND + kb;
    float4 u = *(const float4*)p;
    float4 v = *(const float4*)(p + 4);
    short8 hi, lo;
    split8(u, v, hi, lo);
    whi[t] = hi;
    wlo[t] = lo;
}

// ----------------------------------------------------------------- fused ----
// WAVE-PRIVATE flash: each wave independently processes 8 tiles of 16 rows.
// Per tile: stage own 32-KB LDS slice via global_load_lds (pre-swizzled
// global source, linear LDS dest), vmcnt(0) wait (inline asm; NO block
// barrier -> no foreign vmcnt drains, R10's serialization), split-bf16
// MFMA scores, wave-local softmax (shfl-only), ctx accumulate from the
// same LDS slice. ZERO __syncthreads in the kernel; all state intra-wave.
// Block = 2 waves x 32 KB = 64 KB LDS -> 2 blocks/CU, 4 waves/CU; each
// wave's next fetch overlaps other waves' compute -> HBM stays busy.
__global__ __launch_bounds__(128) void k_fused(
    const float* __restrict__ x, const int* __restrict__ mask,
    const short8* __restrict__ whi, const short8* __restrict__ wlo,
    const float* __restrict__ b1, const float* __restrict__ w2,
    float* __restrict__ scores, float* __restrict__ pctx, float* __restrict__ pml)
{
    __shared__ float4 xbuf[2][TR * ND4];   // 2 waves x 32 KB

    const int tid = threadIdx.x;
    const int wv  = tid >> 6;
    const int l   = tid & 63;
    const int lr  = l & 15;
    const int lq  = l >> 4;
    const int wid = blockIdx.x * 2 + wv;
    const size_t R0 = (size_t)wid * (TR * TPW);

    float4* slice = xbuf[wv];
    const float4* __restrict__ x4 = reinterpret_cast<const float4*>(x);

    float w2v[4], b1v[4];
#pragma unroll
    for (int nt = 0; nt < 4; ++nt) {
        w2v[nt] = w2[nt * 16 + lr];
        b1v[nt] = b1[nt * 16 + lr];
    }

    float m_run = -INFINITY, l_run = 0.f;
    float cx[8];
#pragma unroll
    for (int j = 0; j < 8; ++j) cx[j] = 0.f;

    for (int tile = 0; tile < TPW; ++tile) {
        const size_t row0 = R0 + (size_t)tile * TR;

        // ---- stage own 16-row slice (32 gllds, linear dest, swizzled src).
        // lgkmcnt(0): all prior ds_reads of this slice completed (WAR).
        asm volatile("s_waitcnt lgkmcnt(0)" ::: "memory");
#pragma unroll
        for (int i = 0; i < 32; ++i) {
            int r = i >> 1;                       // row within tile
            int c = (i & 1) * 64 + l;             // linear unit in row
            const float4* src = x4 + (row0 + r) * ND4 + (c ^ (r & 7));
            __builtin_amdgcn_global_load_lds(
                (const __attribute__((address_space(1))) void*)src,
                (__attribute__((address_space(3))) void*)&slice[i * 64],
                16, 0, 0);
        }
        asm volatile("s_waitcnt vmcnt(0)" ::: "memory");
        __builtin_amdgcn_sched_barrier(0);

        // ---- phase A: MFMA scores for the 16 rows (split-bf16, as R9)
        f32x4 acc[4];
#pragma unroll
        for (int nt = 0; nt < 4; ++nt) acc[nt] = (f32x4)0.f;

        for (int ks = 0; ks < 16; ++ks) {
            int ub = ks * 8 + lq * 2;
            float4 ua = slice[lr * ND4 + ((ub)     ^ (lr & 7))];
            float4 uv = slice[lr * ND4 + ((ub + 1) ^ (lr & 7))];
            short8 ahi, alo;
            split8(ua, uv, ahi, alo);
#pragma unroll
            for (int nt = 0; nt < 4; ++nt) {
                short8 bh = whi[(ks * 4 + nt) * 64 + l];
                short8 bl = wlo[(ks * 4 + nt) * 64 + l];
                acc[nt] = __builtin_amdgcn_mfma_f32_16x16x32_bf16(ahi, bh, acc[nt], 0, 0, 0);
                acc[nt] = __builtin_amdgcn_mfma_f32_16x16x32_bf16(ahi, bl, acc[nt], 0, 0, 0);
                acc[nt] = __builtin_amdgcn_mfma_f32_16x16x32_bf16(alo, bh, acc[nt], 0, 0, 0);
            }
        }

        // ---- epilogue + mask + wave-local online softmax (shfl only)
        float ev[4];
        {
            float sval[4];
#pragma unroll
            for (int rg = 0; rg < 4; ++rg) {
                float s = 0.f;
#pragma unroll
                for (int nt = 0; nt < 4; ++nt)
                    s += w2v[nt] * tanhf(acc[nt][rg] + b1v[nt]);
                s += __shfl_xor(s, 1);
                s += __shfl_xor(s, 2);
                s += __shfl_xor(s, 4);
                s += __shfl_xor(s, 8);            // all 16 lr-lanes hold s
                int ridx = lq * 4 + rg;           // row within tile
                bool valid = (mask[row0 + ridx] != 0);
                float sm = valid ? s : -INFINITY;
                if (lr == 0) scores[row0 + ridx] = sm;
                sval[rg] = sm;
            }
            float lm = fmaxf(fmaxf(sval[0], sval[1]), fmaxf(sval[2], sval[3]));
            lm = fmaxf(lm, __shfl_xor(lm, 16));
            lm = fmaxf(lm, __shfl_xor(lm, 32));   // tile max, all lanes
            float m_new = fmaxf(m_run, lm);
            float m_eff = (m_new == -INFINITY) ? 0.f : m_new;
            float scale = expf(m_run - m_eff);    // m_run=-inf -> 0
#pragma unroll
            for (int rg = 0; rg < 4; ++rg) ev[rg] = expf(sval[rg] - m_eff);
            float ls = (ev[0] + ev[1]) + (ev[2] + ev[3]);
            ls += __shfl_xor(ls, 16);
            ls += __shfl_xor(ls, 32);             // sum over 16 rows (exact)
            l_run = l_run * scale + ls;
            m_run = m_new;
#pragma unroll
            for (int j = 0; j < 8; ++j) cx[j] *= scale;
        }

        // ---- ctx accumulate from LDS slice: lane covers d=4l..+3, 256+4l..+3
#pragma unroll
        for (int t = 0; t < TR; ++t) {
            float e = __shfl(ev[t & 3], (t >> 2) * 16);
            float4 xa = slice[t * ND4 + ((l)      ^ (t & 7))];
            float4 xb = slice[t * ND4 + ((l + 64) ^ (t & 7))];
            cx[0] = fmaf(e, xa.x, cx[0]);
            cx[1] = fmaf(e, xa.y, cx[1]);
            cx[2] = fmaf(e, xa.z, cx[2]);
            cx[3] = fmaf(e, xa.w, cx[3]);
            cx[4] = fmaf(e, xb.x, cx[4]);
            cx[5] = fmaf(e, xb.y, cx[5]);
            cx[6] = fmaf(e, xb.z, cx[6]);
            cx[7] = fmaf(e, xb.w, cx[7]);
        }
    }

    // ---- write wave partials
    float4 o0 = {cx[0], cx[1], cx[2], cx[3]};
    float4 o1 = {cx[4], cx[5], cx[6], cx[7]};
    *(float4*)&pctx[(size_t)wid * ND + 4 * l]       = o0;
    *(float4*)&pctx[(size_t)wid * ND + 256 + 4 * l] = o1;
    if (l == 0) {
        pml[wid * 2]     = m_run;
        pml[wid * 2 + 1] = l_run;
    }
}

// ----------------------------------------------------------------- merge ----
__global__ __launch_bounds__(256) void k_merge(
    const float* __restrict__ pctx, const float* __restrict__ pml,
    float* __restrict__ ctx, float* __restrict__ mbden)
{
    int b = blockIdx.x, tid = threadIdx.x;
    float m_b = -INFINITY;
    for (int i = 0; i < NPW; ++i) m_b = fmaxf(m_b, pml[(b * NPW + i) * 2]);
    float denom = 0.f;
    for (int i = 0; i < NPW; ++i) {
        float mi = pml[(b * NPW + i) * 2];
        float li = pml[(b * NPW + i) * 2 + 1];
        denom += li * expf(mi - m_b);             // mi=-inf -> 0
    }
    float inv = 1.f / denom;
    int d0 = 2 * tid;
    float a0 = 0.f, a1 = 0.f;
    for (int i = 0; i < NPW; ++i) {
        float s = expf(pml[(b * NPW + i) * 2] - m_b);
        a0 = fmaf(pctx[(size_t)(b * NPW + i) * ND + d0],     s, a0);
        a1 = fmaf(pctx[(size_t)(b * NPW + i) * ND + d0 + 1], s, a1);
    }
    ctx[(size_t)b * ND + d0]     = a0 * inv;
    ctx[(size_t)b * ND + d0 + 1] = a1 * inv;
    if (tid == 0) {
        mbden[b * 2]     = m_b;
        mbden[b * 2 + 1] = denom;
    }
}

// --------------------------------------------------------------- weights ----
__global__ __launch_bounds__(256) void k_weights(
    const float* __restrict__ scores, const float* __restrict__ mbden,
    float* __restrict__ weights)
{
    int i = blockIdx.x * 256 + threadIdx.x;       // over B*T
    int b = i >> 12;                              // / NT
    float m  = mbden[b * 2];
    float dn = mbden[b * 2 + 1];
    weights[i] = expf(scores[i] - m) / dn;        // s=-inf -> exactly 0
}

// ------------------------------------------------------------------ launch --
extern "C" void kernel_launch(void* const* d_in, const int* in_sizes, int n_in,
                              void* d_out, int out_size, void* d_ws, size_t ws_size,
                              hipStream_t stream)
{
    const float* x    = (const float*)d_in[0];
    const int*   mask = (const int*)d_in[1];
    const float* W1   = (const float*)d_in[2];
    const float* b1   = (const float*)d_in[3];
    const float* w2   = (const float*)d_in[4];

    float* ctx     = (float*)d_out;                   // B*D
    float* weights = (float*)d_out + NB * ND;         // B*T

    float* ws      = (float*)d_ws;
    float* scores  = ws;                              // B*T           (131072)
    float* pctx    = ws + NB * NT;                    // NWAVE*ND      (524288)
    float* pml     = pctx + (size_t)NWAVE * ND;       // NWAVE*2       (2048)
    float* mbden   = pml + NWAVE * 2;                 // NB*2          (64)
    short8* whi    = (short8*)(mbden + NB * 2);       // 64 KB
    short8* wlo    = whi + 16 * 4 * 64;               // 64 KB

    k_prep<<<16, 256, 0, stream>>>(W1, whi, wlo);
    k_fused<<<NWAVE / 2, 128, 0, stream>>>(x, mask, whi, wlo, b1, w2,
                                           scores, pctx, pml);
    k_merge<<<NB, 256, 0, stream>>>(pctx, pml, ctx, mbden);
    k_weights<<<NB * NT / 256, 256, 0, stream>>>(scores, mbden, weights);
}

// Round 12
// 134.753 us; speedup vs baseline: 1.0995x; 1.0995x over previous
//
#include <hip/hip_runtime.h>
#include <math.h>

#define NB 32
#define NT 4096
#define ND 512
#define NA 64
#define ND4 (ND / 4)            // 128 float4 units per x-row
#define WROWS 64                // rows per wave (one-shot tile)
#define NWAVE (NB * NT / WROWS) // 2048 waves
#define NPW (NWAVE / NB)        // 64 wave-partials per batch row

typedef __attribute__((ext_vector_type(8))) short short8;   // 8 bf16
typedef __attribute__((ext_vector_type(4))) float f32x4;    // MFMA acc

// ---- split-bf16 helpers: f = hi(trunc bf16) + lo(RNE bf16 of residual) ----
__device__ __forceinline__ uint rne16(float r) {
    uint v = __float_as_uint(r);
    v += 0x7fffu + ((v >> 16) & 1u);
    return v;
}
__device__ __forceinline__ void split2(float f0, float f1, uint& hw, uint& lw) {
    uint u0 = __float_as_uint(f0), u1 = __float_as_uint(f1);
    hw = (u0 >> 16) | (u1 & 0xffff0000u);
    float r0 = f0 - __uint_as_float(u0 & 0xffff0000u);
    float r1 = f1 - __uint_as_float(u1 & 0xffff0000u);
    lw = (rne16(r0) >> 16) | (rne16(r1) & 0xffff0000u);
}
__device__ __forceinline__ void split8(float4 a, float4 b, short8& hi, short8& lo) {
    union U { short8 s; uint u[4]; } H, L;
    split2(a.x, a.y, H.u[0], L.u[0]);
    split2(a.z, a.w, H.u[1], L.u[1]);
    split2(b.x, b.y, H.u[2], L.u[2]);
    split2(b.z, b.w, H.u[3], L.u[3]);
    hi = H.s; lo = L.s;
}

// ------------------------------------------------------------------ prep ----
// Pack W1 into MFMA B-fragments (hi/lo bf16), fidx == global thread id.
__global__ __launch_bounds__(256) void k_prep(
    const float* __restrict__ W1, short8* __restrict__ whi, short8* __restrict__ wlo)
{
    int t = blockIdx.x * 256 + threadIdx.x;       // 0..4095
    int l  = t & 63;
    int nt = (t >> 6) & 3;
    int ks = t >> 8;
    int a  = nt * 16 + (l & 15);
    int kb = ks * 32 + (l >> 4) * 8;
    const float* p = W1 + a * ND + kb;
    float4 u = *(const float4*)p;
    float4 v = *(const float4*)(p + 4);
    short8 hi, lo;
    split8(u, v, hi, lo);
    whi[t] = hi;
    wlo[t] = lo;
}

// ----------------------------------------------------------------- fused ----
// Each wave owns 64 rows ONCE (single-shot softmax, no online rescale).
// Phase A: split-bf16 MFMA scores reading x global->reg (R9's proven path,
// no LDS staging -> no barriers, high occupancy). Phase S: wave-local
// softmax via shfl; per-row e exchanged through a 256 B/wave LDS scratch
// (write-once, broadcast-read, intra-wave lgkmcnt only; ZERO __syncthreads).
// Phase B: ctx accumulate re-reading the same 64 rows (L2/L3-hot).
// R11 lesson: wave-private LDS staging killed TLP (4 waves/CU, all pipes
// <15%); this keeps 256-thr blocks + tiny LDS -> VGPR-limited occupancy.
__global__ __launch_bounds__(256, 4) void k_fused(
    const float* __restrict__ x, const int* __restrict__ mask,
    const short8* __restrict__ whi, const short8* __restrict__ wlo,
    const float* __restrict__ b1, const float* __restrict__ w2,
    float* __restrict__ scores, float* __restrict__ pctx, float* __restrict__ pml)
{
    __shared__ float elds[4][WROWS];   // 1 KB: per-wave e-broadcast scratch

    const int tid = threadIdx.x;
    const int wv  = tid >> 6;
    const int l   = tid & 63;
    const int lr  = l & 15;
    const int lq  = l >> 4;
    const int wid = blockIdx.x * 4 + wv;
    const size_t row0 = (size_t)wid * WROWS;

    const float4* __restrict__ x4 = reinterpret_cast<const float4*>(x);
    const float* xb = x + (row0 + lr) * ND + lq * 8;

    float w2v[4], b1v[4];
#pragma unroll
    for (int nt = 0; nt < 4; ++nt) {
        w2v[nt] = w2[nt * 16 + lr];
        b1v[nt] = b1[nt * 16 + lr];
    }

    // ---- phase A: MFMA scores for 64 rows (4 M-tiles), split-bf16
    f32x4 acc[4][4];
#pragma unroll
    for (int mt = 0; mt < 4; ++mt)
#pragma unroll
        for (int nt = 0; nt < 4; ++nt) acc[mt][nt] = (f32x4)0.f;

    for (int ks = 0; ks < 16; ++ks) {
        short8 ahi[4], alo[4];
#pragma unroll
        for (int mt = 0; mt < 4; ++mt) {
            const float* p = xb + mt * 16 * ND + ks * 32;
            float4 u = *(const float4*)p;
            float4 v = *(const float4*)(p + 4);
            split8(u, v, ahi[mt], alo[mt]);
        }
#pragma unroll
        for (int nt = 0; nt < 4; ++nt) {
            short8 bh = whi[(ks * 4 + nt) * 64 + l];
            short8 bl = wlo[(ks * 4 + nt) * 64 + l];
#pragma unroll
            for (int mt = 0; mt < 4; ++mt) {
                acc[mt][nt] = __builtin_amdgcn_mfma_f32_16x16x32_bf16(ahi[mt], bh, acc[mt][nt], 0, 0, 0);
                acc[mt][nt] = __builtin_amdgcn_mfma_f32_16x16x32_bf16(ahi[mt], bl, acc[mt][nt], 0, 0, 0);
                acc[mt][nt] = __builtin_amdgcn_mfma_f32_16x16x32_bf16(alo[mt], bh, acc[mt][nt], 0, 0, 0);
            }
        }
    }

    // ---- epilogue: per-row score, mask, store; all 16 lr-lanes hold sval
    float sval[4][4];
#pragma unroll
    for (int mt = 0; mt < 4; ++mt) {
#pragma unroll
        for (int rg = 0; rg < 4; ++rg) {
            float s = 0.f;
#pragma unroll
            for (int nt = 0; nt < 4; ++nt)
                s += w2v[nt] * tanhf(acc[mt][nt][rg] + b1v[nt]);
            s += __shfl_xor(s, 1);
            s += __shfl_xor(s, 2);
            s += __shfl_xor(s, 4);
            s += __shfl_xor(s, 8);
            int ridx = mt * 16 + lq * 4 + rg;
            bool valid = (mask[row0 + ridx] != 0);
            float sm = valid ? s : -INFINITY;
            if (lr == 0) scores[row0 + ridx] = sm;
            sval[mt][rg] = sm;
        }
    }

    // ---- wave-local single-shot softmax (m over 64 rows; shfl over lq)
    float m = -INFINITY;
#pragma unroll
    for (int mt = 0; mt < 4; ++mt)
#pragma unroll
        for (int rg = 0; rg < 4; ++rg) m = fmaxf(m, sval[mt][rg]);
    m = fmaxf(m, __shfl_xor(m, 16));
    m = fmaxf(m, __shfl_xor(m, 32));
    float m_eff = (m == -INFINITY) ? 0.f : m;

    // lane lr==0 of each lq writes e for its 16 rows to the wave scratch
    if (lr == 0) {
#pragma unroll
        for (int mt = 0; mt < 4; ++mt)
#pragma unroll
            for (int rg = 0; rg < 4; ++rg)
                elds[wv][mt * 16 + lq * 4 + rg] = expf(sval[mt][rg] - m_eff);
    }
    asm volatile("s_waitcnt lgkmcnt(0)" ::: "memory");
    __builtin_amdgcn_sched_barrier(0);

    // ---- phase B: ctx accumulate; rows re-read from L2/L3 (just fetched).
    // lane covers d = 4l..4l+3 and 256+4l..+3; e broadcast from LDS.
    float4 ca = {0.f, 0.f, 0.f, 0.f}, cb = {0.f, 0.f, 0.f, 0.f};
    float ls = 0.f;
#pragma unroll 4
    for (int t = 0; t < WROWS; ++t) {
        float e = elds[wv][t];                 // same addr all lanes: broadcast
        float4 xa = x4[(row0 + t) * ND4 + l];
        float4 xv = x4[(row0 + t) * ND4 + 64 + l];
        ls += e;
        ca.x = fmaf(e, xa.x, ca.x);
        ca.y = fmaf(e, xa.y, ca.y);
        ca.z = fmaf(e, xa.z, ca.z);
        ca.w = fmaf(e, xa.w, ca.w);
        cb.x = fmaf(e, xv.x, cb.x);
        cb.y = fmaf(e, xv.y, cb.y);
        cb.z = fmaf(e, xv.z, cb.z);
        cb.w = fmaf(e, xv.w, cb.w);
    }

    *(float4*)&pctx[(size_t)wid * ND + 4 * l]       = ca;
    *(float4*)&pctx[(size_t)wid * ND + 256 + 4 * l] = cb;
    if (l == 0) {
        pml[wid * 2]     = m;
        pml[wid * 2 + 1] = ls;
    }
}

// ----------------------------------------------------------------- merge ----
__global__ __launch_bounds__(256) void k_merge(
    const float* __restrict__ pctx, const float* __restrict__ pml,
    float* __restrict__ ctx, float* __restrict__ mbden)
{
    int b = blockIdx.x, tid = threadIdx.x;
    float m_b = -INFINITY;
    for (int i = 0; i < NPW; ++i) m_b = fmaxf(m_b, pml[(b * NPW + i) * 2]);
    float denom = 0.f;
    for (int i = 0; i < NPW; ++i) {
        float mi = pml[(b * NPW + i) * 2];
        float li = pml[(b * NPW + i) * 2 + 1];
        denom += li * expf(mi - m_b);             // mi=-inf -> 0
    }
    float inv = 1.f / denom;
    int d0 = 2 * tid;
    float a0 = 0.f, a1 = 0.f;
    for (int i = 0; i < NPW; ++i) {
        float s = expf(pml[(b * NPW + i) * 2] - m_b);
        a0 = fmaf(pctx[(size_t)(b * NPW + i) * ND + d0],     s, a0);
        a1 = fmaf(pctx[(size_t)(b * NPW + i) * ND + d0 + 1], s, a1);
    }
    ctx[(size_t)b * ND + d0]     = a0 * inv;
    ctx[(size_t)b * ND + d0 + 1] = a1 * inv;
    if (tid == 0) {
        mbden[b * 2]     = m_b;
        mbden[b * 2 + 1] = denom;
    }
}

// --------------------------------------------------------------- weights ----
__global__ __launch_bounds__(256) void k_weights(
    const float* __restrict__ scores, const float* __restrict__ mbden,
    float* __restrict__ weights)
{
    int i = blockIdx.x * 256 + threadIdx.x;       // over B*T
    int b = i >> 12;                              // / NT
    float m  = mbden[b * 2];
    float dn = mbden[b * 2 + 1];
    weights[i] = expf(scores[i] - m) / dn;        // s=-inf -> exactly 0
}

// ------------------------------------------------------------------ launch --
extern "C" void kernel_launch(void* const* d_in, const int* in_sizes, int n_in,
                              void* d_out, int out_size, void* d_ws, size_t ws_size,
                              hipStream_t stream)
{
    const float* x    = (const float*)d_in[0];
    const int*   mask = (const int*)d_in[1];
    const float* W1   = (const float*)d_in[2];
    const float* b1   = (const float*)d_in[3];
    const float* w2   = (const float*)d_in[4];

    float* ctx     = (float*)d_out;                   // B*D
    float* weights = (float*)d_out + NB * ND;         // B*T

    float* ws      = (float*)d_ws;
    float* scores  = ws;                              // B*T            (131072)
    float* pctx    = ws + NB * NT;                    // NWAVE*ND       (1048576)
    float* pml     = pctx + (size_t)NWAVE * ND;       // NWAVE*2        (4096)
    float* mbden   = pml + NWAVE * 2;                 // NB*2           (64)
    short8* whi    = (short8*)(mbden + NB * 2);       // 64 KB
    short8* wlo    = whi + 16 * 4 * 64;               // 64 KB

    k_prep<<<16, 256, 0, stream>>>(W1, whi, wlo);
    k_fused<<<NWAVE / 4, 256, 0, stream>>>(x, mask, whi, wlo, b1, w2,
                                           scores, pctx, pml);
    k_merge<<<NB, 256, 0, stream>>>(pctx, pml, ctx, mbden);
    k_weights<<<NB * NT / 256, 256, 0, stream>>>(scores, mbden, weights);
}

// Round 13
// 118.838 us; speedup vs baseline: 1.2468x; 1.1339x over previous
//
#include <hip/hip_runtime.h>
#include <math.h>

#define NB 32
#define NT 4096
#define ND 512
#define NA 64
#define ND4 (ND / 4)            // 128 float4 units per x-row
#define NBLK (NB * NT / 64)     // 2048 blocks; block = 4 waves x 16 rows
#define NPW 64                  // block-partials per batch row

typedef __attribute__((ext_vector_type(8))) short short8;   // 8 bf16
typedef __attribute__((ext_vector_type(4))) float f32x4;    // MFMA acc

// ---- split-bf16 helpers: f = hi(trunc bf16) + lo(RNE bf16 of residual) ----
__device__ __forceinline__ uint rne16(float r) {
    uint v = __float_as_uint(r);
    v += 0x7fffu + ((v >> 16) & 1u);
    return v;
}
__device__ __forceinline__ void split2(float f0, float f1, uint& hw, uint& lw) {
    uint u0 = __float_as_uint(f0), u1 = __float_as_uint(f1);
    hw = (u0 >> 16) | (u1 & 0xffff0000u);
    float r0 = f0 - __uint_as_float(u0 & 0xffff0000u);
    float r1 = f1 - __uint_as_float(u1 & 0xffff0000u);
    lw = (rne16(r0) >> 16) | (rne16(r1) & 0xffff0000u);
}
__device__ __forceinline__ void split8(float4 a, float4 b, short8& hi, short8& lo) {
    union U { short8 s; uint u[4]; } H, L;
    split2(a.x, a.y, H.u[0], L.u[0]);
    split2(a.z, a.w, H.u[1], L.u[1]);
    split2(b.x, b.y, H.u[2], L.u[2]);
    split2(b.z, b.w, H.u[3], L.u[3]);
    hi = H.s; lo = L.s;
}

// ------------------------------------------------------------------ prep ----
// Pack W1 into MFMA B-fragments (hi/lo bf16), fidx == global thread id.
__global__ __launch_bounds__(256) void k_prep(
    const float* __restrict__ W1, short8* __restrict__ whi, short8* __restrict__ wlo)
{
    int t = blockIdx.x * 256 + threadIdx.x;       // 0..4095
    int l  = t & 63;
    int nt = (t >> 6) & 3;
    int ks = t >> 8;
    int a  = nt * 16 + (l & 15);
    int kb = ks * 32 + (l >> 4) * 8;
    const float* p = W1 + a * ND + kb;
    float4 u = *(const float4*)p;
    float4 v = *(const float4*)(p + 4);
    short8 hi, lo;
    split8(u, v, hi, lo);
    whi[t] = hi;
    wlo[t] = lo;
}

// ----------------------------------------------------------------- fused ----
// R12 post-mortem: 64 rows/wave -> only 2048 waves = 2/SIMD, latency-bound
// (all pipes <25%). Now: wave owns ONE 16-row M-tile -> 8192 waves = 32/CU.
// Per wave: MFMA scores (split-bf16, global->reg x, no staging), wave-local
// softmax (shfl only), ctx accumulate over own 16 rows (L2/L3-hot re-read).
// The 4 waves of a block then combine via LDS (block-max rescale + tree
// reduce) -> ONE partial per block (keeps pctx at R12's 4 MB). Exactly 2
// __syncthreads per kernel (not per chunk).
__global__ __launch_bounds__(256, 4) void k_fused(
    const float* __restrict__ x, const int* __restrict__ mask,
    const short8* __restrict__ whi, const short8* __restrict__ wlo,
    const float* __restrict__ b1, const float* __restrict__ w2,
    float* __restrict__ scores, float* __restrict__ pctx, float* __restrict__ pml)
{
    __shared__ float ctxl[4][ND];      // 8 KB
    __shared__ float wmx[4], wlx[4];

    const int tid = threadIdx.x;
    const int wv  = tid >> 6;
    const int l   = tid & 63;
    const int lr  = l & 15;
    const int lq  = l >> 4;
    const size_t row0 = (size_t)blockIdx.x * 64 + (size_t)wv * 16;

    const float4* __restrict__ x4 = reinterpret_cast<const float4*>(x);
    const float* xb = x + (row0 + lr) * ND + lq * 8;

    float w2v[4], b1v[4];
#pragma unroll
    for (int nt = 0; nt < 4; ++nt) {
        w2v[nt] = w2[nt * 16 + lr];
        b1v[nt] = b1[nt * 16 + lr];
    }

    // ---- phase A: MFMA scores for the wave's 16 rows, split-bf16
    f32x4 acc[4];
#pragma unroll
    for (int nt = 0; nt < 4; ++nt) acc[nt] = (f32x4)0.f;

    for (int ks = 0; ks < 16; ++ks) {
        const float* p = xb + ks * 32;
        float4 u = *(const float4*)p;
        float4 v = *(const float4*)(p + 4);
        short8 ahi, alo;
        split8(u, v, ahi, alo);
#pragma unroll
        for (int nt = 0; nt < 4; ++nt) {
            short8 bh = whi[(ks * 4 + nt) * 64 + l];
            short8 bl = wlo[(ks * 4 + nt) * 64 + l];
            acc[nt] = __builtin_amdgcn_mfma_f32_16x16x32_bf16(ahi, bh, acc[nt], 0, 0, 0);
            acc[nt] = __builtin_amdgcn_mfma_f32_16x16x32_bf16(ahi, bl, acc[nt], 0, 0, 0);
            acc[nt] = __builtin_amdgcn_mfma_f32_16x16x32_bf16(alo, bh, acc[nt], 0, 0, 0);
        }
    }

    // ---- epilogue: per-row score, mask, store; all 16 lr-lanes hold sval
    float sval[4];
#pragma unroll
    for (int rg = 0; rg < 4; ++rg) {
        float s = 0.f;
#pragma unroll
        for (int nt = 0; nt < 4; ++nt)
            s += w2v[nt] * tanhf(acc[nt][rg] + b1v[nt]);
        s += __shfl_xor(s, 1);
        s += __shfl_xor(s, 2);
        s += __shfl_xor(s, 4);
        s += __shfl_xor(s, 8);
        int ridx = lq * 4 + rg;
        bool valid = (mask[row0 + ridx] != 0);
        float sm = valid ? s : -INFINITY;
        if (lr == 0) scores[row0 + ridx] = sm;
        sval[rg] = sm;
    }

    // ---- wave-local softmax over 16 rows (shfl over lq groups)
    float wm = fmaxf(fmaxf(sval[0], sval[1]), fmaxf(sval[2], sval[3]));
    wm = fmaxf(wm, __shfl_xor(wm, 16));
    wm = fmaxf(wm, __shfl_xor(wm, 32));
    float wm_eff = (wm == -INFINITY) ? 0.f : wm;
    float ev[4];
#pragma unroll
    for (int rg = 0; rg < 4; ++rg) ev[rg] = expf(sval[rg] - wm_eff);
    float wl = (ev[0] + ev[1]) + (ev[2] + ev[3]);
    wl += __shfl_xor(wl, 16);
    wl += __shfl_xor(wl, 32);
    if (l == 0) { wmx[wv] = wm; wlx[wv] = wl; }

    // ---- phase B: ctx over own 16 rows (unscaled); rows are L2/L3-hot
    float4 ca = {0.f, 0.f, 0.f, 0.f}, cb = {0.f, 0.f, 0.f, 0.f};
#pragma unroll
    for (int t = 0; t < 16; ++t) {
        float e = __shfl(ev[t & 3], (t >> 2) * 16);
        float4 xa = x4[(row0 + t) * ND4 + l];
        float4 xv = x4[(row0 + t) * ND4 + 64 + l];
        ca.x = fmaf(e, xa.x, ca.x);
        ca.y = fmaf(e, xa.y, ca.y);
        ca.z = fmaf(e, xa.z, ca.z);
        ca.w = fmaf(e, xa.w, ca.w);
        cb.x = fmaf(e, xv.x, cb.x);
        cb.y = fmaf(e, xv.y, cb.y);
        cb.z = fmaf(e, xv.z, cb.z);
        cb.w = fmaf(e, xv.w, cb.w);
    }

    __syncthreads();                   // wmx/wlx visible
    float mb = fmaxf(fmaxf(wmx[0], wmx[1]), fmaxf(wmx[2], wmx[3]));
    float mb_eff = (mb == -INFINITY) ? 0.f : mb;
    float sw = expf(wm - mb_eff);      // wm=-inf -> 0 (kills NaN for dead waves)
    float4 sa = {ca.x * sw, ca.y * sw, ca.z * sw, ca.w * sw};
    float4 sb = {cb.x * sw, cb.y * sw, cb.z * sw, cb.w * sw};
    *(float4*)&ctxl[wv][4 * l]       = sa;
    *(float4*)&ctxl[wv][256 + 4 * l] = sb;
    __syncthreads();                   // ctxl ready

    // ---- block reduce: thread covers d = tid and tid+256
    float s0 = (ctxl[0][tid] + ctxl[1][tid]) + (ctxl[2][tid] + ctxl[3][tid]);
    int t2 = tid + 256;
    float s1 = (ctxl[0][t2] + ctxl[1][t2]) + (ctxl[2][t2] + ctxl[3][t2]);
    pctx[(size_t)blockIdx.x * ND + tid] = s0;
    pctx[(size_t)blockIdx.x * ND + t2]  = s1;
    if (tid == 0) {
        float lt = wlx[0] * expf(wmx[0] - mb_eff) + wlx[1] * expf(wmx[1] - mb_eff)
                 + wlx[2] * expf(wmx[2] - mb_eff) + wlx[3] * expf(wmx[3] - mb_eff);
        pml[blockIdx.x * 2]     = mb;
        pml[blockIdx.x * 2 + 1] = lt;
    }
}

// ----------------------------------------------------------------- merge ----
__global__ __launch_bounds__(256) void k_merge(
    const float* __restrict__ pctx, const float* __restrict__ pml,
    float* __restrict__ ctx, float* __restrict__ mbden)
{
    int b = blockIdx.x, tid = threadIdx.x;
    float m_b = -INFINITY;
    for (int i = 0; i < NPW; ++i) m_b = fmaxf(m_b, pml[(b * NPW + i) * 2]);
    float denom = 0.f;
    for (int i = 0; i < NPW; ++i) {
        float mi = pml[(b * NPW + i) * 2];
        float li = pml[(b * NPW + i) * 2 + 1];
        denom += li * expf(mi - m_b);             // mi=-inf -> 0
    }
    float inv = 1.f / denom;
    int d0 = 2 * tid;
    float a0 = 0.f, a1 = 0.f;
    for (int i = 0; i < NPW; ++i) {
        float s = expf(pml[(b * NPW + i) * 2] - m_b);
        a0 = fmaf(pctx[(size_t)(b * NPW + i) * ND + d0],     s, a0);
        a1 = fmaf(pctx[(size_t)(b * NPW + i) * ND + d0 + 1], s, a1);
    }
    ctx[(size_t)b * ND + d0]     = a0 * inv;
    ctx[(size_t)b * ND + d0 + 1] = a1 * inv;
    if (tid == 0) {
        mbden[b * 2]     = m_b;
        mbden[b * 2 + 1] = denom;
    }
}

// --------------------------------------------------------------- weights ----
__global__ __launch_bounds__(256) void k_weights(
    const float* __restrict__ scores, const float* __restrict__ mbden,
    float* __restrict__ weights)
{
    int i = blockIdx.x * 256 + threadIdx.x;       // over B*T
    int b = i >> 12;                              // / NT
    float m  = mbden[b * 2];
    float dn = mbden[b * 2 + 1];
    weights[i] = expf(scores[i] - m) / dn;        // s=-inf -> exactly 0
}

// ------------------------------------------------------------------ launch --
extern "C" void kernel_launch(void* const* d_in, const int* in_sizes, int n_in,
                              void* d_out, int out_size, void* d_ws, size_t ws_size,
                              hipStream_t stream)
{
    const float* x    = (const float*)d_in[0];
    const int*   mask = (const int*)d_in[1];
    const float* W1   = (const float*)d_in[2];
    const float* b1   = (const float*)d_in[3];
    const float* w2   = (const float*)d_in[4];

    float* ctx     = (float*)d_out;                   // B*D
    float* weights = (float*)d_out + NB * ND;         // B*T

    float* ws      = (float*)d_ws;
    float* scores  = ws;                              // B*T            (131072)
    float* pctx    = ws + NB * NT;                    // NBLK*ND        (1048576)
    float* pml     = pctx + (size_t)NBLK * ND;        // NBLK*2         (4096)
    float* mbden   = pml + NBLK * 2;                  // NB*2           (64)
    short8* whi    = (short8*)(mbden + NB * 2);       // 64 KB
    short8* wlo    = whi + 16 * 4 * 64;               // 64 KB

    k_prep<<<16, 256, 0, stream>>>(W1, whi, wlo);
    k_fused<<<NBLK, 256, 0, stream>>>(x, mask, whi, wlo, b1, w2,
                                      scores, pctx, pml);
    k_merge<<<NB, 256, 0, stream>>>(pctx, pml, ctx, mbden);
    k_weights<<<NB * NT / 256, 256, 0, stream>>>(scores, mbden, weights);
}

// Round 14
// 112.687 us; speedup vs baseline: 1.3148x; 1.0546x over previous
//
#include <hip/hip_runtime.h>
#include <math.h>

#define NB 32
#define NT 4096
#define ND 512
#define NA 64
#define ND4 (ND / 4)            // 128 float4 units per x-row
#define RPB 128                 // rows per block: 4 waves x 32 rows
#define NBLK (NB * NT / RPB)    // 1024 blocks
#define NPW (NT / RPB)          // 32 block-partials per batch row

typedef __attribute__((ext_vector_type(8))) short short8;   // 8 bf16
typedef __attribute__((ext_vector_type(4))) float f32x4;    // MFMA acc

// ---- split-bf16 helpers: f = hi(trunc bf16) + lo(RNE bf16 of residual) ----
__device__ __forceinline__ uint rne16(float r) {
    uint v = __float_as_uint(r);
    v += 0x7fffu + ((v >> 16) & 1u);
    return v;
}
__device__ __forceinline__ void split2(float f0, float f1, uint& hw, uint& lw) {
    uint u0 = __float_as_uint(f0), u1 = __float_as_uint(f1);
    hw = (u0 >> 16) | (u1 & 0xffff0000u);
    float r0 = f0 - __uint_as_float(u0 & 0xffff0000u);
    float r1 = f1 - __uint_as_float(u1 & 0xffff0000u);
    lw = (rne16(r0) >> 16) | (rne16(r1) & 0xffff0000u);
}
__device__ __forceinline__ void split8(float4 a, float4 b, short8& hi, short8& lo) {
    union U { short8 s; uint u[4]; } H, L;
    split2(a.x, a.y, H.u[0], L.u[0]);
    split2(a.z, a.w, H.u[1], L.u[1]);
    split2(b.x, b.y, H.u[2], L.u[2]);
    split2(b.z, b.w, H.u[3], L.u[3]);
    hi = H.s; lo = L.s;
}

// ------------------------------------------------------------------ prep ----
// Pack W1 into MFMA B-fragments (hi/lo bf16), fidx == global thread id.
__global__ __launch_bounds__(256) void k_prep(
    const float* __restrict__ W1, short8* __restrict__ whi, short8* __restrict__ wlo)
{
    int t = blockIdx.x * 256 + threadIdx.x;       // 0..4095
    int l  = t & 63;
    int nt = (t >> 6) & 3;
    int ks = t >> 8;
    int a  = nt * 16 + (l & 15);
    int kb = ks * 32 + (l >> 4) * 8;
    const float* p = W1 + a * ND + kb;
    float4 u = *(const float4*)p;
    float4 v = *(const float4*)(p + 4);
    short8 hi, lo;
    split8(u, v, hi, lo);
    whi[t] = hi;
    wlo[t] = lo;
}

// ----------------------------------------------------------------- fused ----
// R13 post-mortem: 16 rows/wave -> 1.07 GB of W-fragment L2 traffic and only
// 2 x-load instrs in flight per wave (latency-thin phase A). Now: wave owns
// TWO 16-row M-tiles (32 rows): W L2 traffic halves (537 MB) and phase A
// issues 4 independent x-loads per ks. Grid 1024 blocks x 4 waves = 4096
// waves = 16/CU = 4/SIMD == the __launch_bounds__(256,4) 128-VGPR cap, so
// the allocator target equals the grid-imposed occupancy (no spill, no
// wasted registers). Per wave: MFMA scores (split-bf16, global->reg x),
// shfl-only softmax over its 32 rows, ctx accumulate over the same rows
// (L2/L3-hot re-read). 4 waves combine via LDS (2 __syncthreads total).
__global__ __launch_bounds__(256, 4) void k_fused(
    const float* __restrict__ x, const int* __restrict__ mask,
    const short8* __restrict__ whi, const short8* __restrict__ wlo,
    const float* __restrict__ b1, const float* __restrict__ w2,
    float* __restrict__ scores, float* __restrict__ pctx, float* __restrict__ pml)
{
    __shared__ float ctxl[4][ND];      // 8 KB
    __shared__ float wmx[4], wlx[4];

    const int tid = threadIdx.x;
    const int wv  = tid >> 6;
    const int l   = tid & 63;
    const int lr  = l & 15;
    const int lq  = l >> 4;
    const size_t row0 = (size_t)blockIdx.x * RPB + (size_t)wv * 32;

    const float4* __restrict__ x4 = reinterpret_cast<const float4*>(x);
    const float* xb = x + (row0 + lr) * ND + lq * 8;

    float w2v[4], b1v[4];
#pragma unroll
    for (int nt = 0; nt < 4; ++nt) {
        w2v[nt] = w2[nt * 16 + lr];
        b1v[nt] = b1[nt * 16 + lr];
    }

    // ---- phase A: MFMA scores for the wave's 32 rows (2 M-tiles)
    f32x4 acc[2][4];
#pragma unroll
    for (int mt = 0; mt < 2; ++mt)
#pragma unroll
        for (int nt = 0; nt < 4; ++nt) acc[mt][nt] = (f32x4)0.f;

    for (int ks = 0; ks < 16; ++ks) {
        short8 ahi[2], alo[2];
#pragma unroll
        for (int mt = 0; mt < 2; ++mt) {
            const float* p = xb + mt * 16 * ND + ks * 32;
            float4 u = *(const float4*)p;
            float4 v = *(const float4*)(p + 4);
            split8(u, v, ahi[mt], alo[mt]);
        }
#pragma unroll
        for (int nt = 0; nt < 4; ++nt) {
            short8 bh = whi[(ks * 4 + nt) * 64 + l];
            short8 bl = wlo[(ks * 4 + nt) * 64 + l];
#pragma unroll
            for (int mt = 0; mt < 2; ++mt) {
                acc[mt][nt] = __builtin_amdgcn_mfma_f32_16x16x32_bf16(ahi[mt], bh, acc[mt][nt], 0, 0, 0);
                acc[mt][nt] = __builtin_amdgcn_mfma_f32_16x16x32_bf16(ahi[mt], bl, acc[mt][nt], 0, 0, 0);
                acc[mt][nt] = __builtin_amdgcn_mfma_f32_16x16x32_bf16(alo[mt], bh, acc[mt][nt], 0, 0, 0);
            }
        }
    }

    // ---- epilogue: per-row score, mask, store; all 16 lr-lanes hold sval
    float sval[2][4];
#pragma unroll
    for (int mt = 0; mt < 2; ++mt) {
#pragma unroll
        for (int rg = 0; rg < 4; ++rg) {
            float s = 0.f;
#pragma unroll
            for (int nt = 0; nt < 4; ++nt)
                s += w2v[nt] * tanhf(acc[mt][nt][rg] + b1v[nt]);
            s += __shfl_xor(s, 1);
            s += __shfl_xor(s, 2);
            s += __shfl_xor(s, 4);
            s += __shfl_xor(s, 8);
            int ridx = mt * 16 + lq * 4 + rg;     // row within wave's 32
            bool valid = (mask[row0 + ridx] != 0);
            float sm = valid ? s : -INFINITY;
            if (lr == 0) scores[row0 + ridx] = sm;
            sval[mt][rg] = sm;
        }
    }

    // ---- wave-local softmax over 32 rows (shfl over lq groups)
    float wm = -INFINITY;
#pragma unroll
    for (int mt = 0; mt < 2; ++mt)
#pragma unroll
        for (int rg = 0; rg < 4; ++rg) wm = fmaxf(wm, sval[mt][rg]);
    wm = fmaxf(wm, __shfl_xor(wm, 16));
    wm = fmaxf(wm, __shfl_xor(wm, 32));
    float wm_eff = (wm == -INFINITY) ? 0.f : wm;
    float ev[2][4];
#pragma unroll
    for (int mt = 0; mt < 2; ++mt)
#pragma unroll
        for (int rg = 0; rg < 4; ++rg) ev[mt][rg] = expf(sval[mt][rg] - wm_eff);
    float wl = (ev[0][0] + ev[0][1]) + (ev[0][2] + ev[0][3])
             + (ev[1][0] + ev[1][1]) + (ev[1][2] + ev[1][3]);
    wl += __shfl_xor(wl, 16);
    wl += __shfl_xor(wl, 32);
    if (l == 0) { wmx[wv] = wm; wlx[wv] = wl; }

    // ---- phase B: ctx over own 32 rows (unscaled); rows are L2/L3-hot
    float4 ca = {0.f, 0.f, 0.f, 0.f}, cb = {0.f, 0.f, 0.f, 0.f};
#pragma unroll
    for (int t = 0; t < 32; ++t) {
        float e = __shfl(ev[t >> 4][t & 3], ((t >> 2) & 3) * 16);
        float4 xa = x4[(row0 + t) * ND4 + l];
        float4 xv = x4[(row0 + t) * ND4 + 64 + l];
        ca.x = fmaf(e, xa.x, ca.x);
        ca.y = fmaf(e, xa.y, ca.y);
        ca.z = fmaf(e, xa.z, ca.z);
        ca.w = fmaf(e, xa.w, ca.w);
        cb.x = fmaf(e, xv.x, cb.x);
        cb.y = fmaf(e, xv.y, cb.y);
        cb.z = fmaf(e, xv.z, cb.z);
        cb.w = fmaf(e, xv.w, cb.w);
    }

    __syncthreads();                   // wmx/wlx visible
    float mb = fmaxf(fmaxf(wmx[0], wmx[1]), fmaxf(wmx[2], wmx[3]));
    float mb_eff = (mb == -INFINITY) ? 0.f : mb;
    float sw = expf(wm - mb_eff);      // wm=-inf -> 0 (kills NaN for dead waves)
    float4 sa = {ca.x * sw, ca.y * sw, ca.z * sw, ca.w * sw};
    float4 sb = {cb.x * sw, cb.y * sw, cb.z * sw, cb.w * sw};
    *(float4*)&ctxl[wv][4 * l]       = sa;
    *(float4*)&ctxl[wv][256 + 4 * l] = sb;
    __syncthreads();                   // ctxl ready

    // ---- block reduce: thread covers d = tid and tid+256
    float s0 = (ctxl[0][tid] + ctxl[1][tid]) + (ctxl[2][tid] + ctxl[3][tid]);
    int t2 = tid + 256;
    float s1 = (ctxl[0][t2] + ctxl[1][t2]) + (ctxl[2][t2] + ctxl[3][t2]);
    pctx[(size_t)blockIdx.x * ND + tid] = s0;
    pctx[(size_t)blockIdx.x * ND + t2]  = s1;
    if (tid == 0) {
        float lt = wlx[0] * expf(wmx[0] - mb_eff) + wlx[1] * expf(wmx[1] - mb_eff)
                 + wlx[2] * expf(wmx[2] - mb_eff) + wlx[3] * expf(wmx[3] - mb_eff);
        pml[blockIdx.x * 2]     = mb;
        pml[blockIdx.x * 2 + 1] = lt;
    }
}

// ----------------------------------------------------------------- merge ----
__global__ __launch_bounds__(256) void k_merge(
    const float* __restrict__ pctx, const float* __restrict__ pml,
    float* __restrict__ ctx, float* __restrict__ mbden)
{
    int b = blockIdx.x, tid = threadIdx.x;
    float m_b = -INFINITY;
    for (int i = 0; i < NPW; ++i) m_b = fmaxf(m_b, pml[(b * NPW + i) * 2]);
    float denom = 0.f;
    for (int i = 0; i < NPW; ++i) {
        float mi = pml[(b * NPW + i) * 2];
        float li = pml[(b * NPW + i) * 2 + 1];
        denom += li * expf(mi - m_b);             // mi=-inf -> 0
    }
    float inv = 1.f / denom;
    int d0 = 2 * tid;
    float a0 = 0.f, a1 = 0.f;
    for (int i = 0; i < NPW; ++i) {
        float s = expf(pml[(b * NPW + i) * 2] - m_b);
        a0 = fmaf(pctx[(size_t)(b * NPW + i) * ND + d0],     s, a0);
        a1 = fmaf(pctx[(size_t)(b * NPW + i) * ND + d0 + 1], s, a1);
    }
    ctx[(size_t)b * ND + d0]     = a0 * inv;
    ctx[(size_t)b * ND + d0 + 1] = a1 * inv;
    if (tid == 0) {
        mbden[b * 2]     = m_b;
        mbden[b * 2 + 1] = denom;
    }
}

// --------------------------------------------------------------- weights ----
__global__ __launch_bounds__(256) void k_weights(
    const float* __restrict__ scores, const float* __restrict__ mbden,
    float* __restrict__ weights)
{
    int i = blockIdx.x * 256 + threadIdx.x;       // over B*T
    int b = i >> 12;                              // / NT
    float m  = mbden[b * 2];
    float dn = mbden[b * 2 + 1];
    weights[i] = expf(scores[i] - m) / dn;        // s=-inf -> exactly 0
}

// ------------------------------------------------------------------ launch --
extern "C" void kernel_launch(void* const* d_in, const int* in_sizes, int n_in,
                              void* d_out, int out_size, void* d_ws, size_t ws_size,
                              hipStream_t stream)
{
    const float* x    = (const float*)d_in[0];
    const int*   mask = (const int*)d_in[1];
    const float* W1   = (const float*)d_in[2];
    const float* b1   = (const float*)d_in[3];
    const float* w2   = (const float*)d_in[4];

    float* ctx     = (float*)d_out;                   // B*D
    float* weights = (float*)d_out + NB * ND;         // B*T

    float* ws      = (float*)d_ws;
    float* scores  = ws;                              // B*T            (131072)
    float* pctx    = ws + NB * NT;                    // NBLK*ND        (524288)
    float* pml     = pctx + (size_t)NBLK * ND;        // NBLK*2         (2048)
    float* mbden   = pml + NBLK * 2;                  // NB*2           (64)
    short8* whi    = (short8*)(mbden + NB * 2);       // 64 KB
    short8* wlo    = whi + 16 * 4 * 64;               // 64 KB

    k_prep<<<16, 256, 0, stream>>>(W1, whi, wlo);
    k_fused<<<NBLK, 256, 0, stream>>>(x, mask, whi, wlo, b1, w2,
                                      scores, pctx, pml);
    k_merge<<<NB, 256, 0, stream>>>(pctx, pml, ctx, mbden);
    k_weights<<<NB * NT / 256, 256, 0, stream>>>(scores, mbden, weights);
}

// Round 15
// 109.981 us; speedup vs baseline: 1.3472x; 1.0246x over previous
//
#include <hip/hip_runtime.h>
#include <math.h>

#define NB 32
#define NT 4096
#define ND 512
#define NA 64
#define ND4 (ND / 4)            // 128 float4 units per x-row
#define RPB 128                 // rows per block: 4 waves x 32 rows
#define NBLK (NB * NT / RPB)    // 1024 blocks
#define NPW (NT / RPB)          // 32 block-partials per batch row

typedef __attribute__((ext_vector_type(8))) short short8;   // 8 bf16
typedef __attribute__((ext_vector_type(4))) float f32x4;    // MFMA acc

// ---- split-bf16 via HW packer: f = hi(RNE bf16) + lo(RNE bf16 of resid) ----
// v_cvt_pk_bf16_f32 packs bf16(S0)->D[15:0], bf16(S1)->D[31:16] in ONE op
// (T12 verified gfx950 syntax). split2: 6 VALU ops vs 18 bit-twiddled (R14).
__device__ __forceinline__ uint cvtpk(float f0, float f1) {
    uint r;
    asm("v_cvt_pk_bf16_f32 %0, %1, %2" : "=v"(r) : "v"(f0), "v"(f1));
    return r;
}
__device__ __forceinline__ void split2(float f0, float f1, uint& hw, uint& lw) {
    hw = cvtpk(f0, f1);
    float r0 = f0 - __uint_as_float(hw << 16);
    float r1 = f1 - __uint_as_float(hw & 0xffff0000u);
    lw = cvtpk(r0, r1);
}
__device__ __forceinline__ void split8(float4 a, float4 b, short8& hi, short8& lo) {
    union U { short8 s; uint u[4]; } H, L;
    split2(a.x, a.y, H.u[0], L.u[0]);
    split2(a.z, a.w, H.u[1], L.u[1]);
    split2(b.x, b.y, H.u[2], L.u[2]);
    split2(b.z, b.w, H.u[3], L.u[3]);
    hi = H.s; lo = L.s;
}

// ---- fast tanh: (e^{2z}-1)/(e^{2z}+1), z clamped to +-15 (no inf/NaN) ----
__device__ __forceinline__ float fast_tanh(float z) {
    z = fminf(fmaxf(z, -15.f), 15.f);          // v_med3 idiom
    float t = __expf(2.f * z);                 // v_exp_f32 path
    return (t - 1.f) * __builtin_amdgcn_rcpf(t + 1.f);
}

// ------------------------------------------------------------------ prep ----
// Pack W1 into MFMA B-fragments (hi/lo bf16), fidx == global thread id.
__global__ __launch_bounds__(256) void k_prep(
    const float* __restrict__ W1, short8* __restrict__ whi, short8* __restrict__ wlo)
{
    int t = blockIdx.x * 256 + threadIdx.x;       // 0..4095
    int l  = t & 63;
    int nt = (t >> 6) & 3;
    int ks = t >> 8;
    int a  = nt * 16 + (l & 15);
    int kb = ks * 32 + (l >> 4) * 8;
    const float* p = W1 + a * ND + kb;
    float4 u = *(const float4*)p;
    float4 v = *(const float4*)(p + 4);
    short8 hi, lo;
    split8(u, v, hi, lo);
    whi[t] = hi;
    wlo[t] = lo;
}

// ----------------------------------------------------------------- fused ----
// R14 post-mortem: phase-A was VALU-bound on bf16 SPLIT (~18 ops/pair -> 36
// us/CU) + libm tanhf (~11 us/CU), vs 43 us HBM floor. This round: HW
// cvt_pk packer (6 ops/pair) + 8-op tanh. Structure unchanged from R14:
// wave owns 2 M-tiles (32 rows), 4096 waves, global->reg x, shfl softmax,
// ctx re-read L2/L3-hot, block combine via LDS (2 __syncthreads).
__global__ __launch_bounds__(256, 4) void k_fused(
    const float* __restrict__ x, const int* __restrict__ mask,
    const short8* __restrict__ whi, const short8* __restrict__ wlo,
    const float* __restrict__ b1, const float* __restrict__ w2,
    float* __restrict__ scores, float* __restrict__ pctx, float* __restrict__ pml)
{
    __shared__ float ctxl[4][ND];      // 8 KB
    __shared__ float wmx[4], wlx[4];

    const int tid = threadIdx.x;
    const int wv  = tid >> 6;
    const int l   = tid & 63;
    const int lr  = l & 15;
    const int lq  = l >> 4;
    const size_t row0 = (size_t)blockIdx.x * RPB + (size_t)wv * 32;

    const float4* __restrict__ x4 = reinterpret_cast<const float4*>(x);
    const float* xb = x + (row0 + lr) * ND + lq * 8;

    float w2v[4], b1v[4];
#pragma unroll
    for (int nt = 0; nt < 4; ++nt) {
        w2v[nt] = w2[nt * 16 + lr];
        b1v[nt] = b1[nt * 16 + lr];
    }

    // ---- phase A: MFMA scores for the wave's 32 rows (2 M-tiles)
    f32x4 acc[2][4];
#pragma unroll
    for (int mt = 0; mt < 2; ++mt)
#pragma unroll
        for (int nt = 0; nt < 4; ++nt) acc[mt][nt] = (f32x4)0.f;

    for (int ks = 0; ks < 16; ++ks) {
        short8 ahi[2], alo[2];
#pragma unroll
        for (int mt = 0; mt < 2; ++mt) {
            const float* p = xb + mt * 16 * ND + ks * 32;
            float4 u = *(const float4*)p;
            float4 v = *(const float4*)(p + 4);
            split8(u, v, ahi[mt], alo[mt]);
        }
#pragma unroll
        for (int nt = 0; nt < 4; ++nt) {
            short8 bh = whi[(ks * 4 + nt) * 64 + l];
            short8 bl = wlo[(ks * 4 + nt) * 64 + l];
#pragma unroll
            for (int mt = 0; mt < 2; ++mt) {
                acc[mt][nt] = __builtin_amdgcn_mfma_f32_16x16x32_bf16(ahi[mt], bh, acc[mt][nt], 0, 0, 0);
                acc[mt][nt] = __builtin_amdgcn_mfma_f32_16x16x32_bf16(ahi[mt], bl, acc[mt][nt], 0, 0, 0);
                acc[mt][nt] = __builtin_amdgcn_mfma_f32_16x16x32_bf16(alo[mt], bh, acc[mt][nt], 0, 0, 0);
            }
        }
    }

    // ---- epilogue: per-row score, mask, store; all 16 lr-lanes hold sval
    float sval[2][4];
#pragma unroll
    for (int mt = 0; mt < 2; ++mt) {
#pragma unroll
        for (int rg = 0; rg < 4; ++rg) {
            float s = 0.f;
#pragma unroll
            for (int nt = 0; nt < 4; ++nt)
                s += w2v[nt] * fast_tanh(acc[mt][nt][rg] + b1v[nt]);
            s += __shfl_xor(s, 1);
            s += __shfl_xor(s, 2);
            s += __shfl_xor(s, 4);
            s += __shfl_xor(s, 8);
            int ridx = mt * 16 + lq * 4 + rg;     // row within wave's 32
            bool valid = (mask[row0 + ridx] != 0);
            float sm = valid ? s : -INFINITY;
            if (lr == 0) scores[row0 + ridx] = sm;
            sval[mt][rg] = sm;
        }
    }

    // ---- wave-local softmax over 32 rows (shfl over lq groups)
    float wm = -INFINITY;
#pragma unroll
    for (int mt = 0; mt < 2; ++mt)
#pragma unroll
        for (int rg = 0; rg < 4; ++rg) wm = fmaxf(wm, sval[mt][rg]);
    wm = fmaxf(wm, __shfl_xor(wm, 16));
    wm = fmaxf(wm, __shfl_xor(wm, 32));
    float wm_eff = (wm == -INFINITY) ? 0.f : wm;
    float ev[2][4];
#pragma unroll
    for (int mt = 0; mt < 2; ++mt)
#pragma unroll
        for (int rg = 0; rg < 4; ++rg) ev[mt][rg] = __expf(sval[mt][rg] - wm_eff);
    float wl = (ev[0][0] + ev[0][1]) + (ev[0][2] + ev[0][3])
             + (ev[1][0] + ev[1][1]) + (ev[1][2] + ev[1][3]);
    wl += __shfl_xor(wl, 16);
    wl += __shfl_xor(wl, 32);
    if (l == 0) { wmx[wv] = wm; wlx[wv] = wl; }

    // ---- phase B: ctx over own 32 rows (unscaled); rows are L2/L3-hot
    float4 ca = {0.f, 0.f, 0.f, 0.f}, cb = {0.f, 0.f, 0.f, 0.f};
#pragma unroll
    for (int t = 0; t < 32; ++t) {
        float e = __shfl(ev[t >> 4][t & 3], ((t >> 2) & 3) * 16);
        float4 xa = x4[(row0 + t) * ND4 + l];
        float4 xv = x4[(row0 + t) * ND4 + 64 + l];
        ca.x = fmaf(e, xa.x, ca.x);
        ca.y = fmaf(e, xa.y, ca.y);
        ca.z = fmaf(e, xa.z, ca.z);
        ca.w = fmaf(e, xa.w, ca.w);
        cb.x = fmaf(e, xv.x, cb.x);
        cb.y = fmaf(e, xv.y, cb.y);
        cb.z = fmaf(e, xv.z, cb.z);
        cb.w = fmaf(e, xv.w, cb.w);
    }

    __syncthreads();                   // wmx/wlx visible
    float mb = fmaxf(fmaxf(wmx[0], wmx[1]), fmaxf(wmx[2], wmx[3]));
    float mb_eff = (mb == -INFINITY) ? 0.f : mb;
    float sw = __expf(wm - mb_eff);    // wm=-inf -> 0 (kills NaN for dead waves)
    float4 sa = {ca.x * sw, ca.y * sw, ca.z * sw, ca.w * sw};
    float4 sb = {cb.x * sw, cb.y * sw, cb.z * sw, cb.w * sw};
    *(float4*)&ctxl[wv][4 * l]       = sa;
    *(float4*)&ctxl[wv][256 + 4 * l] = sb;
    __syncthreads();                   // ctxl ready

    // ---- block reduce: thread covers d = tid and tid+256
    float s0 = (ctxl[0][tid] + ctxl[1][tid]) + (ctxl[2][tid] + ctxl[3][tid]);
    int t2 = tid + 256;
    float s1 = (ctxl[0][t2] + ctxl[1][t2]) + (ctxl[2][t2] + ctxl[3][t2]);
    pctx[(size_t)blockIdx.x * ND + tid] = s0;
    pctx[(size_t)blockIdx.x * ND + t2]  = s1;
    if (tid == 0) {
        float lt = wlx[0] * __expf(wmx[0] - mb_eff) + wlx[1] * __expf(wmx[1] - mb_eff)
                 + wlx[2] * __expf(wmx[2] - mb_eff) + wlx[3] * __expf(wmx[3] - mb_eff);
        pml[blockIdx.x * 2]     = mb;
        pml[blockIdx.x * 2 + 1] = lt;
    }
}

// ----------------------------------------------------------------- merge ----
__global__ __launch_bounds__(256) void k_merge(
    const float* __restrict__ pctx, const float* __restrict__ pml,
    float* __restrict__ ctx, float* __restrict__ mbden)
{
    int b = blockIdx.x, tid = threadIdx.x;
    float m_b = -INFINITY;
    for (int i = 0; i < NPW; ++i) m_b = fmaxf(m_b, pml[(b * NPW + i) * 2]);
    float denom = 0.f;
    for (int i = 0; i < NPW; ++i) {
        float mi = pml[(b * NPW + i) * 2];
        float li = pml[(b * NPW + i) * 2 + 1];
        denom += li * expf(mi - m_b);             // mi=-inf -> 0
    }
    float inv = 1.f / denom;
    int d0 = 2 * tid;
    float a0 = 0.f, a1 = 0.f;
    for (int i = 0; i < NPW; ++i) {
        float s = expf(pml[(b * NPW + i) * 2] - m_b);
        a0 = fmaf(pctx[(size_t)(b * NPW + i) * ND + d0],     s, a0);
        a1 = fmaf(pctx[(size_t)(b * NPW + i) * ND + d0 + 1], s, a1);
    }
    ctx[(size_t)b * ND + d0]     = a0 * inv;
    ctx[(size_t)b * ND + d0 + 1] = a1 * inv;
    if (tid == 0) {
        mbden[b * 2]     = m_b;
        mbden[b * 2 + 1] = denom;
    }
}

// --------------------------------------------------------------- weights ----
__global__ __launch_bounds__(256) void k_weights(
    const float* __restrict__ scores, const float* __restrict__ mbden,
    float* __restrict__ weights)
{
    int i = blockIdx.x * 256 + threadIdx.x;       // over B*T
    int b = i >> 12;                              // / NT
    float m  = mbden[b * 2];
    float dn = mbden[b * 2 + 1];
    weights[i] = expf(scores[i] - m) / dn;        // s=-inf -> exactly 0
}

// ------------------------------------------------------------------ launch --
extern "C" void kernel_launch(void* const* d_in, const int* in_sizes, int n_in,
                              void* d_out, int out_size, void* d_ws, size_t ws_size,
                              hipStream_t stream)
{
    const float* x    = (const float*)d_in[0];
    const int*   mask = (const int*)d_in[1];
    const float* W1   = (const float*)d_in[2];
    const float* b1   = (const float*)d_in[3];
    const float* w2   = (const float*)d_in[4];

    float* ctx     = (float*)d_out;                   // B*D
    float* weights = (float*)d_out + NB * ND;         // B*T

    float* ws      = (float*)d_ws;
    float* scores  = ws;                              // B*T            (131072)
    float* pctx    = ws + NB * NT;                    // NBLK*ND        (524288)
    float* pml     = pctx + (size_t)NBLK * ND;        // NBLK*2         (2048)
    float* mbden   = pml + NBLK * 2;                  // NB*2           (64)
    short8* whi    = (short8*)(mbden + NB * 2);       // 64 KB
    short8* wlo    = whi + 16 * 4 * 64;               // 64 KB

    k_prep<<<16, 256, 0, stream>>>(W1, whi, wlo);
    k_fused<<<NBLK, 256, 0, stream>>>(x, mask, whi, wlo, b1, w2,
                                      scores, pctx, pml);
    k_merge<<<NB, 256, 0, stream>>>(pctx, pml, ctx, mbden);
    k_weights<<<NB * NT / 256, 256, 0, stream>>>(scores, mbden, weights);
}